// Round 10
// baseline (487.132 us; speedup 1.0000x reference)
//
#include <hip/hip_runtime.h>
#include <math.h>

#define N_NODES  50000
#define N_EDGES  800000
#define HIDDEN   128
#define N_LAYERS 3
#define N_MASKED 25000
#define N_GRAPHS 64

// ordered float<->uint mapping (monotonic): preserves IEEE total order
__device__ __forceinline__ unsigned fmap(float f) {
    unsigned u = __float_as_uint(f);
    return (u & 0x80000000u) ? ~u : (u | 0x80000000u);
}
__device__ __forceinline__ float funmap(unsigned u) {
    return __uint_as_float((u & 0x80000000u) ? (u & 0x7FFFFFFFu) : ~u);
}

// ---------------- degree count (in-degree via dst) ----------------
__global__ void count_deg_kernel(const int* __restrict__ dst, unsigned* __restrict__ deg) {
    int i = blockIdx.x * blockDim.x + threadIdx.x;
    if (i < N_EDGES) atomicAdd(&deg[dst[i]], 1u);
}

__global__ void dinv_kernel(const unsigned* __restrict__ deg, float* __restrict__ dinv) {
    int i = blockIdx.x * blockDim.x + threadIdx.x;
    if (i < N_NODES) dinv[i] = rsqrtf((float)(deg[i] + 1u));   // +1 self-loop
}

// ---------------- prefix sum: per-block inclusive scan ----------------
__global__ void scan_block_kernel(const unsigned* __restrict__ deg, unsigned* __restrict__ incl,
                                  unsigned* __restrict__ bsum) {
    __shared__ unsigned s[1024];
    int i = blockIdx.x * 1024 + threadIdx.x;
    unsigned v = (i < N_NODES) ? deg[i] : 0u;
    s[threadIdx.x] = v;
    __syncthreads();
    for (int off = 1; off < 1024; off <<= 1) {
        unsigned t = (threadIdx.x >= off) ? s[threadIdx.x - off] : 0u;
        __syncthreads();
        s[threadIdx.x] += t;
        __syncthreads();
    }
    if (i < N_NODES) incl[i] = s[threadIdx.x];
    if (threadIdx.x == 1023) bsum[blockIdx.x] = s[1023];
}

__global__ void scan_bsum_kernel(unsigned* __restrict__ bsum, int n) {
    if (blockIdx.x == 0 && threadIdx.x == 0) {
        unsigned run = 0;
        for (int i = 0; i < n; ++i) { unsigned t = bsum[i]; bsum[i] = run; run += t; }
    }
}

__global__ void scan_finalize_kernel(const unsigned* __restrict__ incl,
                                     const unsigned* __restrict__ bsum_ex,
                                     unsigned* __restrict__ row_ptr,
                                     unsigned* __restrict__ cursor) {
    int i = blockIdx.x * blockDim.x + threadIdx.x;
    if (i <= N_NODES) {
        unsigned v = (i == 0) ? 0u : incl[i - 1] + bsum_ex[(i - 1) >> 10];
        row_ptr[i] = v;
        if (i < N_NODES) cursor[i] = v;
    }
}

// ---------------- CSR fill ----------------
__global__ void fill_csr_kernel(const int* __restrict__ src, const int* __restrict__ dst,
                                unsigned* __restrict__ cursor, int* __restrict__ csr_src) {
    int e = blockIdx.x * blockDim.x + threadIdx.x;
    if (e < N_EDGES) {
        unsigned p = atomicAdd(&cursor[dst[e]], 1u);
        csr_src[p] = src[e];
    }
}

// ---------------- GEMM, col-split, templated epilogue ----------------
// MODE 0: Out[r] = dinv[r] * (A[r] @ W)                      (pre-scale for gather)
// MODE 1: Out[r] = dinv[r] * ELU((A[r] @ W) + bias)          (layer epilogue + pre-scale)
// MODE 2: atomicMax(gmax[batch[r]], fmap(ELU((A@W) + bias))) (masked last layer + pool)
#define ASTRIDE 132   // 128 + 4 pad
template<int MODE>
__global__ __launch_bounds__(256) void gemm128_kernel(const float* __restrict__ A,
                                                      const float* __restrict__ W,
                                                      const float* __restrict__ dinv,
                                                      const float* __restrict__ bias,
                                                      const int* __restrict__ batch,
                                                      unsigned* __restrict__ gmax,
                                                      float* __restrict__ Out,
                                                      int nrows) {
    __shared__ float Wl[128 * 64];      // 32 KB, k-major slice
    __shared__ float Rb[32 * ASTRIDE];  // 16.5 KB
    const int tid = threadIdx.x;
    const int rowBase = (blockIdx.x >> 1) * 32;
    const int colHalf = (blockIdx.x & 1) * 64;
    if (rowBase >= nrows) return;

    for (int i = tid * 4; i < 128 * 64; i += 256 * 4) {
        int k = i >> 6, c = i & 63;
        *(float4*)&Wl[i] = *(const float4*)&W[(size_t)k * 128 + colHalf + c];
    }
    for (int i = tid * 4; i < 32 * 128; i += 256 * 4) {
        int r = i >> 7, col = i & 127;
        int row = rowBase + r;
        float4 v = make_float4(0.f, 0.f, 0.f, 0.f);
        if (row < nrows) v = *(const float4*)&A[(size_t)row * 128 + col];
        *(float4*)&Rb[r * ASTRIDE + col] = v;
    }
    __syncthreads();

    const int c4 = (tid & 15) * 4;   // col group within 64
    const int rr = tid >> 4;         // row slot 0..15; rows rr, rr+16

    float4 acc0 = make_float4(0, 0, 0, 0), acc1 = make_float4(0, 0, 0, 0);

    #pragma unroll 4
    for (int k4 = 0; k4 < 128; k4 += 4) {
        float h0[4], h1[4];
        *(float4*)h0 = *(const float4*)&Rb[rr * ASTRIDE + k4];
        *(float4*)h1 = *(const float4*)&Rb[(rr + 16) * ASTRIDE + k4];
        #pragma unroll
        for (int j = 0; j < 4; ++j) {
            float4 wv = *(const float4*)&Wl[(k4 + j) * 64 + c4];
            acc0.x += h0[j] * wv.x; acc0.y += h0[j] * wv.y;
            acc0.z += h0[j] * wv.z; acc0.w += h0[j] * wv.w;
            acc1.x += h1[j] * wv.x; acc1.y += h1[j] * wv.y;
            acc1.z += h1[j] * wv.z; acc1.w += h1[j] * wv.w;
        }
    }

    #pragma unroll
    for (int m = 0; m < 2; ++m) {
        int r0 = rowBase + rr + m * 16;
        if (r0 >= nrows) continue;
        float4 o = (m == 0) ? acc0 : acc1;
        if (MODE == 0) {
            float d = dinv[r0];
            o.x *= d; o.y *= d; o.z *= d; o.w *= d;
            *(float4*)&Out[(size_t)r0 * 128 + colHalf + c4] = o;
        } else {
            float4 bb = *(const float4*)&bias[colHalf + c4];
            o.x += bb.x; o.y += bb.y; o.z += bb.z; o.w += bb.w;
            o.x = o.x > 0.f ? o.x : expm1f(o.x);
            o.y = o.y > 0.f ? o.y : expm1f(o.y);
            o.z = o.z > 0.f ? o.z : expm1f(o.z);
            o.w = o.w > 0.f ? o.w : expm1f(o.w);
            if (MODE == 1) {
                float d = dinv[r0];
                o.x *= d; o.y *= d; o.z *= d; o.w *= d;
                *(float4*)&Out[(size_t)r0 * 128 + colHalf + c4] = o;
            } else {
                unsigned* gm = &gmax[batch[r0] * 128 + colHalf + c4];
                atomicMax(&gm[0], fmap(o.x));
                atomicMax(&gm[1], fmap(o.y));
                atomicMax(&gm[2], fmap(o.z));
                atomicMax(&gm[3], fmap(o.w));
            }
        }
    }
}

// ---------------- CSR gather (round-5 shape), templated epilogue ----------------
// sumall = tab[v] + sum_{s in N(v)} tab[s]   (tab rows already carry dinv_s)
// GMODE 0 (ELU):  out[w] = dinv_v * ELU(dinv_v * sumall + bias)   (layer1 + pre-scale)
// GMODE 1 (RAW):  out[w] = dinv_v * sumall                        (feeds a GEMM)
template<int GMODE>
__global__ __launch_bounds__(256) void gather_kernel(const float* __restrict__ tab,
                                                     const unsigned* __restrict__ row_ptr,
                                                     const int* __restrict__ csr_src,
                                                     const float* __restrict__ dinv,
                                                     const float* __restrict__ bias,
                                                     float* __restrict__ out,
                                                     const int* __restrict__ nodes,
                                                     int n_items) {
    int wid = (blockIdx.x * blockDim.x + threadIdx.x) >> 6;
    int w = wid >> 1;
    if (w >= n_items) return;
    const int f = ((wid & 1) << 6) | (threadIdx.x & 63);
    const int v = nodes ? nodes[w] : w;

    const unsigned s0 = row_ptr[v], e0 = row_ptr[v + 1];
    const float* __restrict__ base = tab + f;

    float acc[8];
    #pragma unroll
    for (int j = 0; j < 8; ++j) acc[j] = 0.f;
    acc[0] = base[(size_t)v << 7];   // self-loop row

    unsigned i = s0;
    if (i + 8 <= e0) {
        int idx[8];
        #pragma unroll
        for (int j = 0; j < 8; ++j) idx[j] = csr_src[i + j];
        for (; i + 16 <= e0; i += 8) {
            int nxt[8];
            #pragma unroll
            for (int j = 0; j < 8; ++j) nxt[j] = csr_src[i + 8 + j];
            #pragma unroll
            for (int j = 0; j < 8; ++j) acc[j] += base[(size_t)idx[j] << 7];
            #pragma unroll
            for (int j = 0; j < 8; ++j) idx[j] = nxt[j];
        }
        #pragma unroll
        for (int j = 0; j < 8; ++j) acc[j] += base[(size_t)idx[j] << 7];
        i += 8;
    }
    if (i + 4 <= e0) {
        #pragma unroll
        for (int j = 0; j < 4; ++j) acc[j] += base[(size_t)csr_src[i + j] << 7];
        i += 4;
    }
    for (; i < e0; ++i) acc[0] += base[(size_t)csr_src[i] << 7];

    float dv = dinv[v];
    float sumall = ((acc[0] + acc[1]) + (acc[2] + acc[3])) +
                   ((acc[4] + acc[5]) + (acc[6] + acc[7]));
    float o;
    if (GMODE == 0) {
        o = dv * sumall + bias[f];
        o = o > 0.f ? o : expm1f(o);
        o *= dv;                       // pre-scale for the next layer's gather
    } else {
        o = dv * sumall;               // raw A_norm row, feeds GEMM
    }
    out[((size_t)w << 7) + f] = o;
}

// ---------------- init gmax to mapped(-inf) ----------------
__global__ void gmax_init_kernel(unsigned* __restrict__ gmax) {
    int i = blockIdx.x * blockDim.x + threadIdx.x;
    if (i < N_GRAPHS * 128) gmax[i] = 0x007FFFFFu;  // fmap(-inf)
}

// ---------------- finish: out[g] = sum_f unmap(gmax[g][f]) * w[f] + b ----------------
__global__ void pool_finish_kernel(const unsigned* __restrict__ gmax,
                                   const float* __restrict__ w, const float* __restrict__ b,
                                   float* __restrict__ out) {
    const int g = blockIdx.x;
    const int f = threadIdx.x;
    float val = funmap(gmax[g * 128 + f]) * w[f];
    #pragma unroll
    for (int off = 32; off > 0; off >>= 1) val += __shfl_down(val, off);
    __shared__ float ps[2];
    if ((threadIdx.x & 63) == 0) ps[threadIdx.x >> 6] = val;
    __syncthreads();
    if (threadIdx.x == 0) out[g] = ps[0] + ps[1] + b[0];
}

extern "C" void kernel_launch(void* const* d_in, const int* in_sizes, int n_in,
                              void* d_out, int out_size, void* d_ws, size_t ws_size,
                              hipStream_t stream) {
    const float* x      = (const float*)d_in[0];
    const int*   ei     = (const int*)d_in[1];
    const int*   mask   = (const int*)d_in[2];
    const int*   batch  = (const int*)d_in[3];
    const float* conv_w = (const float*)d_in[4];
    const float* conv_b = (const float*)d_in[5];
    const float* lt1_w  = (const float*)d_in[6];
    const float* lt1_b  = (const float*)d_in[7];
    float* out = (float*)d_out;

    const int* e_src = ei;
    const int* e_dst = ei + N_EDGES;

    // ---- workspace carve-up (aligned to 256B) ----
    char* ws = (char*)d_ws;
    auto carve = [&](size_t bytes) { char* p = ws; ws += (bytes + 255) & ~(size_t)255; return p; };
    unsigned* deg     = (unsigned*)carve(N_NODES * 4);
    float*    dinv    = (float*)   carve(N_NODES * 4);
    unsigned* row_ptr = (unsigned*)carve((N_NODES + 1) * 4);
    unsigned* cursor  = (unsigned*)carve(N_NODES * 4);
    unsigned* bsum    = (unsigned*)carve(64 * 4);
    unsigned* gmax    = (unsigned*)carve(N_GRAPHS * 128 * 4);
    int*      csr_src = (int*)     carve((size_t)N_EDGES * 4);
    float*    bufA    = (float*)   carve((size_t)N_NODES * HIDDEN * 4);
    float*    bufB    = (float*)   carve((size_t)N_NODES * HIDDEN * 4);
    unsigned* incl    = (unsigned*)csr_src;  // alias: dead before fill_csr runs

    const int NB_SCAN = (N_NODES + 1023) / 1024;  // 49

    // ---- build dinv + CSR ----
    hipMemsetAsync(deg, 0, N_NODES * sizeof(unsigned), stream);
    count_deg_kernel<<<(N_EDGES + 255) / 256, 256, 0, stream>>>(e_dst, deg);
    dinv_kernel<<<(N_NODES + 255) / 256, 256, 0, stream>>>(deg, dinv);
    scan_block_kernel<<<NB_SCAN, 1024, 0, stream>>>(deg, incl, bsum);
    scan_bsum_kernel<<<1, 64, 0, stream>>>(bsum, NB_SCAN);
    scan_finalize_kernel<<<(N_NODES + 256) / 256, 256, 0, stream>>>(incl, bsum, row_ptr, cursor);
    fill_csr_kernel<<<(N_EDGES + 255) / 256, 256, 0, stream>>>(e_src, e_dst, cursor, csr_src);
    gmax_init_kernel<<<(N_GRAPHS * 128 + 255) / 256, 256, 0, stream>>>(gmax);

    const int GB_FULL = ((N_NODES + 31) / 32) * 2;     // GEMM blocks, 50k rows
    const int GB_MASK = ((N_MASKED + 31) / 32) * 2;    // GEMM blocks, 25k rows
    const int GA_FULL = (N_NODES * 2 * 64 + 255) / 256;
    const int GA_MASK = (N_MASKED * 2 * 64 + 255) / 256;

    // L1: bufA = dinv*(x@W1);  bufB = dinv*ELU(dinv*Agg(bufA) + b1)
    gemm128_kernel<0><<<GB_FULL, 256, 0, stream>>>(x, conv_w, dinv, nullptr, nullptr,
                                                   nullptr, bufA, N_NODES);
    gather_kernel<0><<<GA_FULL, 256, 0, stream>>>(bufA, row_ptr, csr_src, dinv,
                                                  conv_b, bufB, nullptr, N_NODES);
    // L2 (gather-first): bufA = Agg(bufB);  bufB = dinv*ELU(bufA@W2 + b2)
    gather_kernel<1><<<GA_FULL, 256, 0, stream>>>(bufB, row_ptr, csr_src, dinv,
                                                  nullptr, bufA, nullptr, N_NODES);
    gemm128_kernel<1><<<GB_FULL, 256, 0, stream>>>(bufA, conv_w + 128 * 128, dinv,
                                                   conv_b + HIDDEN, nullptr, nullptr,
                                                   bufB, N_NODES);
    // L3 (gather-first, masked): bufA = Agg_mask(bufB);  pool(ELU(bufA@W3 + b3))
    gather_kernel<1><<<GA_MASK, 256, 0, stream>>>(bufB, row_ptr, csr_src, dinv,
                                                  nullptr, bufA, mask, N_MASKED);
    gemm128_kernel<2><<<GB_MASK, 256, 0, stream>>>(bufA, conv_w + 2 * 128 * 128, nullptr,
                                                   conv_b + 2 * HIDDEN, batch, gmax,
                                                   nullptr, N_MASKED);

    pool_finish_kernel<<<N_GRAPHS, HIDDEN, 0, stream>>>(gmax, lt1_w, lt1_b, out);
}

// Round 11
// 394.660 us; speedup vs baseline: 1.2343x; 1.2343x over previous
//
#include <hip/hip_runtime.h>
#include <math.h>

#define N_NODES  50000
#define N_EDGES  800000
#define HIDDEN   128
#define N_LAYERS 3
#define N_MASKED 25000
#define N_GRAPHS 64

typedef __attribute__((ext_vector_type(8))) short bf16x8;
typedef __attribute__((ext_vector_type(4))) float f32x4;

// ordered float<->uint mapping (monotonic): preserves IEEE total order
__device__ __forceinline__ unsigned fmap(float f) {
    unsigned u = __float_as_uint(f);
    return (u & 0x80000000u) ? ~u : (u | 0x80000000u);
}
__device__ __forceinline__ float funmap(unsigned u) {
    return __uint_as_float((u & 0x80000000u) ? (u & 0x7FFFFFFFu) : ~u);
}

// split f32 -> bf16 hi (RNE) + bf16 lo (RNE of remainder), packed hi | lo<<16
__device__ __forceinline__ unsigned pack_split(float x) {
    unsigned u = __float_as_uint(x);
    unsigned hi = (u + 0x7fffu + ((u >> 16) & 1u)) >> 16;
    float rem = x - __uint_as_float(hi << 16);
    unsigned v = __float_as_uint(rem);
    unsigned lo = (v + 0x7fffu + ((v >> 16) & 1u)) >> 16;
    return hi | (lo << 16);
}

// ---------------- degree count (in-degree via dst) ----------------
__global__ void count_deg_kernel(const int* __restrict__ dst, unsigned* __restrict__ deg) {
    int i = blockIdx.x * blockDim.x + threadIdx.x;
    if (i < N_EDGES) atomicAdd(&deg[dst[i]], 1u);
}

__global__ void dinv_kernel(const unsigned* __restrict__ deg, float* __restrict__ dinv) {
    int i = blockIdx.x * blockDim.x + threadIdx.x;
    if (i < N_NODES) dinv[i] = rsqrtf((float)(deg[i] + 1u));   // +1 self-loop
}

// ---------------- prefix sum: per-block inclusive scan ----------------
__global__ void scan_block_kernel(const unsigned* __restrict__ deg, unsigned* __restrict__ incl,
                                  unsigned* __restrict__ bsum) {
    __shared__ unsigned s[1024];
    int i = blockIdx.x * 1024 + threadIdx.x;
    unsigned v = (i < N_NODES) ? deg[i] : 0u;
    s[threadIdx.x] = v;
    __syncthreads();
    for (int off = 1; off < 1024; off <<= 1) {
        unsigned t = (threadIdx.x >= off) ? s[threadIdx.x - off] : 0u;
        __syncthreads();
        s[threadIdx.x] += t;
        __syncthreads();
    }
    if (i < N_NODES) incl[i] = s[threadIdx.x];
    if (threadIdx.x == 1023) bsum[blockIdx.x] = s[1023];
}

__global__ void scan_bsum_kernel(unsigned* __restrict__ bsum, int n) {
    if (blockIdx.x == 0 && threadIdx.x == 0) {
        unsigned run = 0;
        for (int i = 0; i < n; ++i) { unsigned t = bsum[i]; bsum[i] = run; run += t; }
    }
}

__global__ void scan_finalize_kernel(const unsigned* __restrict__ incl,
                                     const unsigned* __restrict__ bsum_ex,
                                     unsigned* __restrict__ row_ptr,
                                     unsigned* __restrict__ cursor) {
    int i = blockIdx.x * blockDim.x + threadIdx.x;
    if (i <= N_NODES) {
        unsigned v = (i == 0) ? 0u : incl[i - 1] + bsum_ex[(i - 1) >> 10];
        row_ptr[i] = v;
        if (i < N_NODES) cursor[i] = v;
    }
}

// ---------------- CSR fill ----------------
__global__ void fill_csr_kernel(const int* __restrict__ src, const int* __restrict__ dst,
                                unsigned* __restrict__ cursor, int* __restrict__ csr_src) {
    int e = blockIdx.x * blockDim.x + threadIdx.x;
    if (e < N_EDGES) {
        unsigned p = atomicAdd(&cursor[dst[e]], 1u);
        csr_src[p] = src[e];
    }
}

// ---------------- W repack into MFMA B-fragment order + hi/lo split ----------------
// layout: [layer][kstep(4)][ctile(8)][lane(64)][j(8)]; B[k][n], k=ks*32+(lane>>4)*8+j,
// n=ct*16+(lane&15). 16384 ushort per layer per half.
__global__ void wprep_kernel(const float* __restrict__ W,
                             unsigned short* __restrict__ Whi,
                             unsigned short* __restrict__ Wlo) {
    int idx = blockIdx.x * 256 + threadIdx.x;
    if (idx >= 3 * 16384) return;
    int j     = idx & 7;
    int lane  = (idx >> 3) & 63;
    int ct    = (idx >> 9) & 7;
    int ks    = (idx >> 12) & 3;
    int layer = idx >> 14;
    int k = ks * 32 + (lane >> 4) * 8 + j;
    int n = ct * 16 + (lane & 15);
    unsigned p = pack_split(W[layer * 16384 + k * 128 + n]);
    Whi[idx] = (unsigned short)(p & 0xffffu);
    Wlo[idx] = (unsigned short)(p >> 16);
}

// ---------------- x -> packed split-bf16 ----------------
__global__ void xpack_kernel(const float* __restrict__ x, unsigned* __restrict__ xp, int n) {
    int i = blockIdx.x * 256 + threadIdx.x;
    if (i < n) xp[i] = pack_split(x[i]);
}

// ---------------- MFMA GEMM: C[nrows x 128] = unpack(Ap) @ W, templated epilogue ----
// MODE 0: Out[r] = dinv[r] * C[r]
// MODE 1: Out[r] = dinv[r] * ELU(C[r] + bias)
// MODE 2: atomicMax(gmax[batch[r]], fmap(ELU(C[r] + bias)))
// Per wave: 16 rows x 128 cols = 8 tiles of 16x16x32, K=128 in 4 steps,
// 3 MFMA per tile-step (Ahi*Whi + Alo*Whi + Ahi*Wlo). No LDS, no barriers.
template<int MODE>
__global__ __launch_bounds__(256) void mfma_gemm_kernel(const unsigned* __restrict__ Ap,
                                                        const unsigned short* __restrict__ Wh,
                                                        const unsigned short* __restrict__ Wl,
                                                        const float* __restrict__ dinv,
                                                        const float* __restrict__ bias,
                                                        const int* __restrict__ batch,
                                                        unsigned* __restrict__ gmax,
                                                        float* __restrict__ Out,
                                                        int nrows) {
    const int lane = threadIdx.x & 63;
    const int wv = threadIdx.x >> 6;
    const int rowBase = blockIdx.x * 64 + wv * 16;
    if (rowBase >= nrows) return;

    int arow = rowBase + (lane & 15);
    if (arow > nrows - 1) arow = nrows - 1;          // clamp, stores guarded below
    const unsigned* aptr = Ap + (size_t)arow * 128 + (lane >> 4) * 8;

    f32x4 acc[8];
    #pragma unroll
    for (int c = 0; c < 8; ++c) acc[c] = (f32x4){0.f, 0.f, 0.f, 0.f};

    #pragma unroll
    for (int ks = 0; ks < 4; ++ks) {
        uint4 pa0 = *(const uint4*)(aptr + ks * 32);
        uint4 pa1 = *(const uint4*)(aptr + ks * 32 + 4);
        unsigned pv[8] = {pa0.x, pa0.y, pa0.z, pa0.w, pa1.x, pa1.y, pa1.z, pa1.w};
        bf16x8 ah, al;
        #pragma unroll
        for (int j = 0; j < 8; ++j) {
            ah[j] = (short)(pv[j] & 0xffffu);
            al[j] = (short)(pv[j] >> 16);
        }
        const unsigned short* wbh = Wh + ks * 4096 + lane * 8;
        const unsigned short* wbl = Wl + ks * 4096 + lane * 8;
        #pragma unroll
        for (int ct = 0; ct < 8; ++ct) {
            bf16x8 bh = *(const bf16x8*)(wbh + ct * 512);
            bf16x8 bl = *(const bf16x8*)(wbl + ct * 512);
            acc[ct] = __builtin_amdgcn_mfma_f32_16x16x32_bf16(ah, bh, acc[ct], 0, 0, 0);
            acc[ct] = __builtin_amdgcn_mfma_f32_16x16x32_bf16(al, bh, acc[ct], 0, 0, 0);
            acc[ct] = __builtin_amdgcn_mfma_f32_16x16x32_bf16(ah, bl, acc[ct], 0, 0, 0);
        }
    }

    // C/D layout: col = lane&15, row = (lane>>4)*4 + reg   [m89-verified]
    const int colBase = lane & 15;
    const int rgrp = lane >> 4;
    #pragma unroll
    for (int r = 0; r < 4; ++r) {
        int row = rowBase + rgrp * 4 + r;
        if (row >= nrows) continue;
        float d = 0.f;
        int bofs = 0;
        if (MODE == 0 || MODE == 1) d = dinv[row];
        if (MODE == 2) bofs = batch[row] * 128;
        #pragma unroll
        for (int ct = 0; ct < 8; ++ct) {
            int col = ct * 16 + colBase;
            float o = acc[ct][r];
            if (MODE == 0) {
                Out[(size_t)row * 128 + col] = o * d;
            } else {
                o += bias[col];
                o = o > 0.f ? o : expm1f(o);
                if (MODE == 1) Out[(size_t)row * 128 + col] = o * d;
                else           atomicMax(&gmax[bofs + col], fmap(o));
            }
        }
    }
}

// ---------------- CSR gather (round-5 shape), templated epilogue ----------------
// sumall = tab[v] + sum_{s in N(v)} tab[s]   (tab rows already carry dinv_s)
// GMODE 0: outf[w] = dinv_v * ELU(dinv_v * sumall + bias)   (f32 table out)
// GMODE 1: outp[w] = pack_split(dinv_v * sumall)            (packed GEMM input out)
template<int GMODE>
__global__ __launch_bounds__(256) void gather_kernel(const float* __restrict__ tab,
                                                     const unsigned* __restrict__ row_ptr,
                                                     const int* __restrict__ csr_src,
                                                     const float* __restrict__ dinv,
                                                     const float* __restrict__ bias,
                                                     float* __restrict__ outf,
                                                     unsigned* __restrict__ outp,
                                                     const int* __restrict__ nodes,
                                                     int n_items) {
    int wid = (blockIdx.x * blockDim.x + threadIdx.x) >> 6;
    int w = wid >> 1;
    if (w >= n_items) return;
    const int f = ((wid & 1) << 6) | (threadIdx.x & 63);
    const int v = nodes ? nodes[w] : w;

    const unsigned s0 = row_ptr[v], e0 = row_ptr[v + 1];
    const float* __restrict__ base = tab + f;

    float acc[8];
    #pragma unroll
    for (int j = 0; j < 8; ++j) acc[j] = 0.f;
    acc[0] = base[(size_t)v << 7];   // self-loop row

    unsigned i = s0;
    if (i + 8 <= e0) {
        int idx[8];
        #pragma unroll
        for (int j = 0; j < 8; ++j) idx[j] = csr_src[i + j];
        for (; i + 16 <= e0; i += 8) {
            int nxt[8];
            #pragma unroll
            for (int j = 0; j < 8; ++j) nxt[j] = csr_src[i + 8 + j];
            #pragma unroll
            for (int j = 0; j < 8; ++j) acc[j] += base[(size_t)idx[j] << 7];
            #pragma unroll
            for (int j = 0; j < 8; ++j) idx[j] = nxt[j];
        }
        #pragma unroll
        for (int j = 0; j < 8; ++j) acc[j] += base[(size_t)idx[j] << 7];
        i += 8;
    }
    if (i + 4 <= e0) {
        #pragma unroll
        for (int j = 0; j < 4; ++j) acc[j] += base[(size_t)csr_src[i + j] << 7];
        i += 4;
    }
    for (; i < e0; ++i) acc[0] += base[(size_t)csr_src[i] << 7];

    float dv = dinv[v];
    float sumall = ((acc[0] + acc[1]) + (acc[2] + acc[3])) +
                   ((acc[4] + acc[5]) + (acc[6] + acc[7]));
    if (GMODE == 0) {
        float o = dv * sumall + bias[f];
        o = o > 0.f ? o : expm1f(o);
        outf[((size_t)w << 7) + f] = o * dv;   // pre-scale for next aggregation
    } else {
        outp[((size_t)w << 7) + f] = pack_split(dv * sumall);
    }
}

// ---------------- init gmax to mapped(-inf) ----------------
__global__ void gmax_init_kernel(unsigned* __restrict__ gmax) {
    int i = blockIdx.x * blockDim.x + threadIdx.x;
    if (i < N_GRAPHS * 128) gmax[i] = 0x007FFFFFu;  // fmap(-inf)
}

// ---------------- finish: out[g] = sum_f unmap(gmax[g][f]) * w[f] + b ----------------
__global__ void pool_finish_kernel(const unsigned* __restrict__ gmax,
                                   const float* __restrict__ w, const float* __restrict__ b,
                                   float* __restrict__ out) {
    const int g = blockIdx.x;
    const int f = threadIdx.x;
    float val = funmap(gmax[g * 128 + f]) * w[f];
    #pragma unroll
    for (int off = 32; off > 0; off >>= 1) val += __shfl_down(val, off);
    __shared__ float ps[2];
    if ((threadIdx.x & 63) == 0) ps[threadIdx.x >> 6] = val;
    __syncthreads();
    if (threadIdx.x == 0) out[g] = ps[0] + ps[1] + b[0];
}

extern "C" void kernel_launch(void* const* d_in, const int* in_sizes, int n_in,
                              void* d_out, int out_size, void* d_ws, size_t ws_size,
                              hipStream_t stream) {
    const float* x      = (const float*)d_in[0];
    const int*   ei     = (const int*)d_in[1];
    const int*   mask   = (const int*)d_in[2];
    const int*   batch  = (const int*)d_in[3];
    const float* conv_w = (const float*)d_in[4];
    const float* conv_b = (const float*)d_in[5];
    const float* lt1_w  = (const float*)d_in[6];
    const float* lt1_b  = (const float*)d_in[7];
    float* out = (float*)d_out;

    const int* e_src = ei;
    const int* e_dst = ei + N_EDGES;

    // ---- workspace carve-up (aligned to 256B) ----
    char* ws = (char*)d_ws;
    auto carve = [&](size_t bytes) { char* p = ws; ws += (bytes + 255) & ~(size_t)255; return p; };
    unsigned* deg     = (unsigned*)carve(N_NODES * 4);
    float*    dinv    = (float*)   carve(N_NODES * 4);
    unsigned* row_ptr = (unsigned*)carve((N_NODES + 1) * 4);
    unsigned* cursor  = (unsigned*)carve(N_NODES * 4);
    unsigned* bsum    = (unsigned*)carve(64 * 4);
    unsigned* gmax    = (unsigned*)carve(N_GRAPHS * 128 * 4);
    unsigned short* wph = (unsigned short*)carve(3 * 16384 * 2);
    unsigned short* wpl = (unsigned short*)carve(3 * 16384 * 2);
    int*      csr_src = (int*)     carve((size_t)N_EDGES * 4);
    char*     reg1    = carve((size_t)N_NODES * HIDDEN * 4);   // region 1 (25.6 MB)
    char*     reg2    = carve((size_t)N_NODES * HIDDEN * 4);   // region 2 (25.6 MB)
    unsigned* incl    = (unsigned*)csr_src;  // alias: dead before fill_csr runs

    // region lifetimes (no overlap conflicts):
    //   reg1: xp (packed x) -> bufB (gather0 f32 out) -> bufB2 (GEMM2 f32 out)
    //   reg2: bufA (GEMM1 f32 out) -> bufAp (gather1 packed out) -> bufCp (masked packed out)
    unsigned* xp    = (unsigned*)reg1;
    float*    bufB  = (float*)reg1;
    float*    bufB2 = (float*)reg1;
    float*    bufA  = (float*)reg2;
    unsigned* bufAp = (unsigned*)reg2;
    unsigned* bufCp = (unsigned*)reg2;

    const int NB_SCAN = (N_NODES + 1023) / 1024;  // 49

    // ---- build dinv + CSR + W-prep ----
    hipMemsetAsync(deg, 0, N_NODES * sizeof(unsigned), stream);
    count_deg_kernel<<<(N_EDGES + 255) / 256, 256, 0, stream>>>(e_dst, deg);
    dinv_kernel<<<(N_NODES + 255) / 256, 256, 0, stream>>>(deg, dinv);
    scan_block_kernel<<<NB_SCAN, 1024, 0, stream>>>(deg, incl, bsum);
    scan_bsum_kernel<<<1, 64, 0, stream>>>(bsum, NB_SCAN);
    scan_finalize_kernel<<<(N_NODES + 256) / 256, 256, 0, stream>>>(incl, bsum, row_ptr, cursor);
    fill_csr_kernel<<<(N_EDGES + 255) / 256, 256, 0, stream>>>(e_src, e_dst, cursor, csr_src);
    gmax_init_kernel<<<(N_GRAPHS * 128 + 255) / 256, 256, 0, stream>>>(gmax);
    wprep_kernel<<<(3 * 16384 + 255) / 256, 256, 0, stream>>>(conv_w, wph, wpl);
    xpack_kernel<<<(N_NODES * HIDDEN + 255) / 256, 256, 0, stream>>>(x, xp, N_NODES * HIDDEN);

    const int GEMM_FULL = (N_NODES + 63) / 64;
    const int GEMM_MASK = (N_MASKED + 63) / 64;
    const int GA_FULL = (N_NODES * 2 * 64 + 255) / 256;
    const int GA_MASK = (N_MASKED * 2 * 64 + 255) / 256;

    // L1: bufA = dinv*(x@W1)
    mfma_gemm_kernel<0><<<GEMM_FULL, 256, 0, stream>>>(xp, wph, wpl, dinv, nullptr,
                                                       nullptr, nullptr, bufA, N_NODES);
    // bufB = dinv*ELU(dinv*Agg(bufA) + b1)
    gather_kernel<0><<<GA_FULL, 256, 0, stream>>>(bufA, row_ptr, csr_src, dinv,
                                                  conv_b, bufB, nullptr, nullptr, N_NODES);
    // L2 gather-first: bufAp = pack(Agg(bufB))
    gather_kernel<1><<<GA_FULL, 256, 0, stream>>>(bufB, row_ptr, csr_src, dinv,
                                                  nullptr, nullptr, bufAp, nullptr, N_NODES);
    // bufB2 = dinv*ELU(bufAp@W2 + b2)
    mfma_gemm_kernel<1><<<GEMM_FULL, 256, 0, stream>>>(bufAp, wph + 16384, wpl + 16384, dinv,
                                                       conv_b + HIDDEN, nullptr, nullptr,
                                                       bufB2, N_NODES);
    // L3 gather-first masked: bufCp = pack(Agg_mask(bufB2))
    gather_kernel<1><<<GA_MASK, 256, 0, stream>>>(bufB2, row_ptr, csr_src, dinv,
                                                  nullptr, nullptr, bufCp, mask, N_MASKED);
    // pool(ELU(bufCp@W3 + b3)) via atomicMax
    mfma_gemm_kernel<2><<<GEMM_MASK, 256, 0, stream>>>(bufCp, wph + 32768, wpl + 32768, nullptr,
                                                       conv_b + 2 * HIDDEN, batch, gmax,
                                                       nullptr, N_MASKED);

    pool_finish_kernel<<<N_GRAPHS, HIDDEN, 0, stream>>>(gmax, lt1_w, lt1_b, out);
}